// Round 1
// baseline (119.899 us; speedup 1.0000x reference)
//
#include <hip/hip_runtime.h>

// Problem: B=8, CTX=1024, D=512 RoPE attention head, fp32 in/out, bf16-tolerance.
#define BATCH 8
#define CTXN  1024
#define DMODEL 512

using short8 = __attribute__((ext_vector_type(8))) short;
using f32x4  = __attribute__((ext_vector_type(4))) float;

typedef const void __attribute__((address_space(1)))* as1_cvp;
typedef void __attribute__((address_space(3)))* as3_vp;

__device__ __forceinline__ unsigned short f2bf(float f) {
  unsigned int u = __float_as_uint(f);
  u += 0x7fffu + ((u >> 16) & 1u);   // round-to-nearest-even
  return (unsigned short)(u >> 16);
}

// ---------------- prep kernels ----------------

// Extract cos/sin from the block-diagonal R: R[c,2i,2i]=cos, R[c,2i+1,2i]=sin.
__global__ __launch_bounds__(256) void prep_table(const float* __restrict__ R,
                                                  float2* __restrict__ tab) {
  int c = blockIdx.x;          // 1024 blocks
  int i = threadIdx.x;         // 256 = D/2
  size_t base = (size_t)c * (DMODEL * DMODEL);
  float cs = R[base + (size_t)1026 * i];          // (2i)*512 + 2i
  float sn = R[base + (size_t)1026 * i + 512];    // (2i+1)*512 + 2i
  tab[c * 256 + i] = make_float2(cs, sn);
}

// fp32 -> bf16 cast, 4-wide.
__global__ __launch_bounds__(256) void prep_cast(const float* __restrict__ src,
                                                 unsigned short* __restrict__ dst, int n4) {
  int gid = blockIdx.x * 256 + threadIdx.x;
  if (gid >= n4) return;
  float4 f = ((const float4*)src)[gid];
  ushort4 u;
  u.x = f2bf(f.x); u.y = f2bf(f.y); u.z = f2bf(f.z); u.w = f2bf(f.w);
  ((ushort4*)dst)[gid] = u;
}

// ---------------- GEMM core helpers (m97 structure) ----------------

// Stage a [128][32] bf16 tile (8 KB) from global (row stride ld) into LDS, linear layout.
__device__ __forceinline__ void stage128x32(const unsigned short* g, int ld,
                                            unsigned short* s, int t) {
#pragma unroll
  for (int c = 0; c < 2; ++c) {
    int li  = t + (c << 8);          // 0..511, 16B each
    int row = li >> 2;
    int col = (li & 3) << 3;
    const unsigned short* gp = g + (size_t)row * ld + col;
    unsigned short* lp = s + (li << 3);
    __builtin_amdgcn_global_load_lds((as1_cvp)gp, (as3_vp)lp, 16, 0, 0);
  }
}

// One K=32 step: 4 A-frags, 4 B-frags, 16 MFMA. Both tiles K-contiguous [128][32].
__device__ __forceinline__ void mfma_step(const unsigned short* sA, const unsigned short* sB,
                                          int wr, int wc, int l, f32x4 acc[4][4]) {
  int rl = l & 15;
  int ko = (l >> 4) << 3;
  short8 af[4], bfr[4];
#pragma unroll
  for (int m = 0; m < 4; ++m)
    af[m] = *(const short8*)(sA + (wr * 64 + m * 16 + rl) * 32 + ko);
#pragma unroll
  for (int n = 0; n < 4; ++n)
    bfr[n] = *(const short8*)(sB + (wc * 64 + n * 16 + rl) * 32 + ko);
#pragma unroll
  for (int m = 0; m < 4; ++m)
#pragma unroll
    for (int n = 0; n < 4; ++n)
      acc[m][n] = __builtin_amdgcn_mfma_f32_16x16x32_bf16(af[m], bfr[n], acc[m][n], 0, 0, 0);
}

// ---------------- K2: QKV projection + bias + RoPE, V transposed ----------------
// C = Xbf16 [8192,512] @ Wall^T [1536,512].  n in [0,512)=q, [512,1024)=k, [1024,1536)=v.
__global__ __launch_bounds__(256) void qkv_kernel(const unsigned short* __restrict__ xb,
                                                  const unsigned short* __restrict__ wb,
                                                  const float* __restrict__ bq,
                                                  const float* __restrict__ bk,
                                                  const float* __restrict__ bv,
                                                  const float2* __restrict__ tab,
                                                  unsigned short* __restrict__ qrot,
                                                  unsigned short* __restrict__ krot,
                                                  unsigned short* __restrict__ vt) {
  __shared__ __align__(16) unsigned short sA[128 * 32];
  __shared__ __align__(16) unsigned short sB[128 * 32];
  int t = threadIdx.x, w = t >> 6, l = t & 63, wr = w >> 1, wc = w & 1;
  int m0 = blockIdx.x * 128, n0 = blockIdx.y * 128;
  f32x4 acc[4][4] = {};
  for (int k0 = 0; k0 < 512; k0 += 32) {
    stage128x32(xb + (size_t)m0 * 512 + k0, 512, sA, t);
    stage128x32(wb + (size_t)n0 * 512 + k0, 512, sB, t);
    __syncthreads();
    mfma_step(sA, sB, wr, wc, l, acc);
    __syncthreads();
  }
  int sec = n0 >> 9;  // 0=q 1=k 2=v (tiles never straddle sections: 512%128==0)
  const float* bias = (sec == 0) ? bq : (sec == 1) ? bk : bv;
  unsigned short* qk_dst = (sec == 0) ? qrot : krot;
  int col_l = l & 15, rgrp = (l >> 4) << 2;
#pragma unroll
  for (int n = 0; n < 4; ++n) {
    int eg = n0 + wc * 64 + n * 16 + col_l;
    int e  = eg & 511;
    float bsv = bias[e];
    if (sec < 2) {
      int i = e >> 1;
#pragma unroll
      for (int m = 0; m < 4; ++m) {
        int rowb = m0 + wr * 64 + m * 16 + rgrp;
#pragma unroll
        for (int r = 0; r < 4; ++r) {
          int mg = rowb + r;
          int cpos = mg & (CTXN - 1);
          float val  = acc[m][n][r] + bsv;
          float part = __shfl_xor(val, 1);
          float2 cs  = tab[cpos * 256 + i];
          float o = (e & 1) ? fmaf(part, cs.y, val * cs.x)    //  q2i*sin + q2i1*cos
                            : fmaf(-part, cs.y, val * cs.x);  //  q2i*cos - q2i1*sin
          qk_dst[(size_t)mg * 512 + e] = f2bf(o);
        }
      }
    } else {
#pragma unroll
      for (int m = 0; m < 4; ++m) {
        int rowb = m0 + wr * 64 + m * 16 + rgrp;
        int bidx = rowb >> 10;
        int cpos = rowb & (CTXN - 1);
        ushort4 pk;
        pk.x = f2bf(acc[m][n][0] + bsv);
        pk.y = f2bf(acc[m][n][1] + bsv);
        pk.z = f2bf(acc[m][n][2] + bsv);
        pk.w = f2bf(acc[m][n][3] + bsv);
        *(ushort4*)(vt + ((size_t)bidx * 512 + e) * 1024 + cpos) = pk;  // vt[b][d][c]
      }
    }
  }
}

// ---------------- K3: scores = qrot @ krot^T * scale (triangular tiles) ----------------
__global__ __launch_bounds__(256) void scores_kernel(const unsigned short* __restrict__ qr,
                                                     const unsigned short* __restrict__ kr,
                                                     float* __restrict__ S) {
  int it = blockIdx.x, jt = blockIdx.y, b = blockIdx.z;
  if (jt > it) return;
  __shared__ __align__(16) unsigned short sA[128 * 32];
  __shared__ __align__(16) unsigned short sB[128 * 32];
  int t = threadIdx.x, w = t >> 6, l = t & 63, wr = w >> 1, wc = w & 1;
  const unsigned short* A  = qr + ((size_t)b << 19) + (size_t)it * 128 * 512;
  const unsigned short* Bp = kr + ((size_t)b << 19) + (size_t)jt * 128 * 512;
  f32x4 acc[4][4] = {};
  for (int k0 = 0; k0 < 512; k0 += 32) {
    stage128x32(A + k0, 512, sA, t);
    stage128x32(Bp + k0, 512, sB, t);
    __syncthreads();
    mfma_step(sA, sB, wr, wc, l, acc);
    __syncthreads();
  }
  const float scale = 0.04419417382415922f;  // 1/sqrt(512)
  float* Sb = S + ((size_t)b << 20);
  int col_l = l & 15, rgrp = (l >> 4) << 2;
#pragma unroll
  for (int m = 0; m < 4; ++m) {
    int iq = it * 128 + wr * 64 + m * 16 + rgrp;
#pragma unroll
    for (int n = 0; n < 4; ++n) {
      int j = jt * 128 + wc * 64 + n * 16 + col_l;
#pragma unroll
      for (int r = 0; r < 4; ++r)
        Sb[(size_t)(iq + r) * 1024 + j] = acc[m][n][r] * scale;
    }
  }
}

// ---------------- K4: causal row softmax, fp32 -> bf16 P ----------------
__global__ __launch_bounds__(256) void softmax_kernel(const float* __restrict__ S,
                                                      unsigned short* __restrict__ P) {
  int i = blockIdx.x, b = blockIdx.y, t = threadIdx.x;
  const float* row = S + ((size_t)b << 20) + (size_t)i * 1024;
  unsigned short* prow = P + ((size_t)b << 20) + (size_t)i * 1024;
  int len  = i + 1;
  int jmax = ((i >> 7) + 1) << 7;  // zero-fill to end of diagonal 128-tile (PV reads it)
  __shared__ float red[256];
  float mx = -3.4e38f;
  for (int j = t; j < len; j += 256) mx = fmaxf(mx, row[j]);
  red[t] = mx; __syncthreads();
  for (int s = 128; s > 0; s >>= 1) { if (t < s) red[t] = fmaxf(red[t], red[t + s]); __syncthreads(); }
  mx = red[0]; __syncthreads();
  float sm = 0.f;
  for (int j = t; j < len; j += 256) sm += expf(row[j] - mx);
  red[t] = sm; __syncthreads();
  for (int s = 128; s > 0; s >>= 1) { if (t < s) red[t] += red[t + s]; __syncthreads(); }
  float inv = 1.0f / red[0];
  for (int j = t; j < jmax; j += 256) {
    float p = (j < len) ? expf(row[j] - mx) * inv : 0.0f;
    prow[j] = f2bf(p);
  }
}

// ---------------- K5: out = P @ V  (A=P [1024,1024] bf16, B=vt [512,1024] = V^T) ----------------
__global__ __launch_bounds__(256) void pv_kernel(const unsigned short* __restrict__ P,
                                                 const unsigned short* __restrict__ vt,
                                                 float* __restrict__ out) {
  int it = blockIdx.x, nt = blockIdx.y, b = blockIdx.z;
  __shared__ __align__(16) unsigned short sA[128 * 32];
  __shared__ __align__(16) unsigned short sB[128 * 32];
  int t = threadIdx.x, w = t >> 6, l = t & 63, wr = w >> 1, wc = w & 1;
  const unsigned short* A  = P  + ((size_t)b << 20) + (size_t)it * 128 * 1024;
  const unsigned short* Bp = vt + ((size_t)b << 19) + (size_t)nt * 128 * 1024;
  int kend = (it + 1) << 7;  // causal: j < (it+1)*128
  f32x4 acc[4][4] = {};
  for (int k0 = 0; k0 < kend; k0 += 32) {
    stage128x32(A + k0, 1024, sA, t);
    stage128x32(Bp + k0, 1024, sB, t);
    __syncthreads();
    mfma_step(sA, sB, wr, wc, l, acc);
    __syncthreads();
  }
  float* ob = out + ((size_t)b << 19);
  int col_l = l & 15, rgrp = (l >> 4) << 2;
#pragma unroll
  for (int m = 0; m < 4; ++m) {
    int iq = it * 128 + wr * 64 + m * 16 + rgrp;
#pragma unroll
    for (int n = 0; n < 4; ++n) {
      int d = nt * 128 + wc * 64 + n * 16 + col_l;
#pragma unroll
      for (int r = 0; r < 4; ++r)
        ob[(size_t)(iq + r) * 512 + d] = acc[m][n][r];
    }
  }
}

// ---------------- launch ----------------
extern "C" void kernel_launch(void* const* d_in, const int* in_sizes, int n_in,
                              void* d_out, int out_size, void* d_ws, size_t ws_size,
                              hipStream_t stream) {
  const float* x  = (const float*)d_in[0];
  const float* wq = (const float*)d_in[1];
  const float* bq = (const float*)d_in[2];
  const float* wk = (const float*)d_in[3];
  const float* bk = (const float*)d_in[4];
  const float* wv = (const float*)d_in[5];
  const float* bv = (const float*)d_in[6];
  const float* R  = (const float*)d_in[7];
  float* out = (float*)d_out;

  char* ws = (char*)d_ws;
  float2*         tab  = (float2*)(ws);                          //  2 MB
  unsigned short* xb   = (unsigned short*)(ws + (2ull  << 20));  //  8 MB
  unsigned short* wb   = (unsigned short*)(ws + (10ull << 20));  //  1.5 MB
  unsigned short* qrot = (unsigned short*)(ws + (12ull << 20));  //  8 MB
  unsigned short* krot = (unsigned short*)(ws + (20ull << 20));  //  8 MB
  unsigned short* vt   = (unsigned short*)(ws + (28ull << 20));  //  8 MB
  float*          S    = (float*)(ws + (36ull << 20));           // 32 MB
  unsigned short* P    = (unsigned short*)(ws + (68ull << 20));  // 16 MB -> total 84 MB

  // prep
  prep_table<<<dim3(CTXN), dim3(256), 0, stream>>>(R, tab);
  prep_cast<<<dim3(4096), dim3(256), 0, stream>>>(x, xb, 1048576);
  prep_cast<<<dim3(256), dim3(256), 0, stream>>>(wq, wb,            65536);
  prep_cast<<<dim3(256), dim3(256), 0, stream>>>(wk, wb + 262144,   65536);
  prep_cast<<<dim3(256), dim3(256), 0, stream>>>(wv, wb + 524288,   65536);

  // QKV + RoPE
  qkv_kernel<<<dim3(64, 12), dim3(256), 0, stream>>>(xb, wb, bq, bk, bv, tab, qrot, krot, vt);

  // scores (lower-triangular tiles only)
  scores_kernel<<<dim3(8, 8, BATCH), dim3(256), 0, stream>>>(qrot, krot, S);

  // causal softmax
  softmax_kernel<<<dim3(CTXN, BATCH), dim3(256), 0, stream>>>(S, P);

  // PV
  pv_kernel<<<dim3(8, 4, BATCH), dim3(256), 0, stream>>>(P, vt, out);
}

// Round 2
// 99.078 us; speedup vs baseline: 1.2101x; 1.2101x over previous
//
#include <hip/hip_runtime.h>

// Problem: B=8, CTX=1024, D=512 RoPE attention head, fp32 in/out, bf16-tolerance.
#define BATCH 8
#define CTXN  1024
#define DMODEL 512

using short8 = __attribute__((ext_vector_type(8))) short;
using f32x4  = __attribute__((ext_vector_type(4))) float;

typedef const void __attribute__((address_space(1)))* as1_cvp;
typedef void __attribute__((address_space(3)))* as3_vp;

__device__ __forceinline__ unsigned short f2bf(float f) {
  unsigned int u = __float_as_uint(f);
  u += 0x7fffu + ((u >> 16) & 1u);   // round-to-nearest-even
  return (unsigned short)(u >> 16);
}

// ---------------- prep kernels ----------------

// Build cos/sin table on device (matches ref's fp32 theta to ~1ulp; avoids the
// 64MB strided gather from the 1GB R input entirely).
__global__ __launch_bounds__(256) void prep_table(float2* __restrict__ tab) {
  int c = blockIdx.x;          // 1024
  int i = threadIdx.x;         // 256 = D/2
  // theta = c * 10000^(-i/256) = c * exp2(-i * log2(10000)/256)
  float freq = exp2f((float)i * (-13.287712379549449f / 256.0f));
  float th = (float)c * freq;
  float sn, cs;
  sincosf(th, &sn, &cs);       // accurate version (Payne-Hanek for large args)
  tab[c * 256 + i] = make_float2(cs, sn);
}

// fp32 -> bf16 cast for x + 3 weights in ONE launch.
#define X4  1048576   // 8*1024*512/4
#define W4  65536     // 512*512/4
__global__ __launch_bounds__(256) void prep_cast_all(const float* __restrict__ x,
                                                     const float* __restrict__ wq,
                                                     const float* __restrict__ wk,
                                                     const float* __restrict__ wv,
                                                     unsigned short* __restrict__ xb,
                                                     unsigned short* __restrict__ wb) {
  int gid = blockIdx.x * 256 + threadIdx.x;
  const float4* src; ushort4* dst;
  if (gid < X4)                { src = (const float4*)x  + gid;              dst = (ushort4*)xb + gid; }
  else if (gid < X4 + W4)      { int o = gid - X4;       src = (const float4*)wq + o; dst = (ushort4*)wb + o; }
  else if (gid < X4 + 2 * W4)  { int o = gid - X4 - W4;  src = (const float4*)wk + o; dst = (ushort4*)(wb + 262144) + o; }
  else                         { int o = gid - X4 - 2*W4; src = (const float4*)wv + o; dst = (ushort4*)(wb + 524288) + o; }
  float4 f = *src;
  ushort4 u;
  u.x = f2bf(f.x); u.y = f2bf(f.y); u.z = f2bf(f.z); u.w = f2bf(f.w);
  *dst = u;
}

// ---------------- GEMM core helpers (m97 structure, BK=64) ----------------

// Stage a [128][64] bf16 tile (16 KB) from global (row stride ld) into LDS, linear.
__device__ __forceinline__ void stage128x64(const unsigned short* g, int ld,
                                            unsigned short* s, int t) {
#pragma unroll
  for (int c = 0; c < 4; ++c) {
    int li  = t + (c << 8);          // 0..1023, 16B chunks
    int row = li >> 3;               // 8 chunks per 128B row
    int col = (li & 7) << 3;
    __builtin_amdgcn_global_load_lds((as1_cvp)(g + (size_t)row * ld + col),
                                     (as3_vp)(s + (li << 3)), 16, 0, 0);
  }
}

// One K=64 step: 2 sub-steps of {4 A-frags, 4 B-frags, 16 MFMA}. Tiles [128][64].
__device__ __forceinline__ void mfma_step64(const unsigned short* sA, const unsigned short* sB,
                                            int wr, int wc, int l, f32x4 acc[4][4]) {
  int rl = l & 15;
  int ko = (l >> 4) << 3;
#pragma unroll
  for (int kk = 0; kk < 64; kk += 32) {
    short8 af[4], bfr[4];
#pragma unroll
    for (int m = 0; m < 4; ++m)
      af[m] = *(const short8*)(sA + (wr * 64 + m * 16 + rl) * 64 + kk + ko);
#pragma unroll
    for (int n = 0; n < 4; ++n)
      bfr[n] = *(const short8*)(sB + (wc * 64 + n * 16 + rl) * 64 + kk + ko);
#pragma unroll
    for (int m = 0; m < 4; ++m)
#pragma unroll
      for (int n = 0; n < 4; ++n)
        acc[m][n] = __builtin_amdgcn_mfma_f32_16x16x32_bf16(af[m], bfr[n], acc[m][n], 0, 0, 0);
  }
}

// ---------------- K2: QKV projection + bias + RoPE, V transposed ----------------
// C = Xbf16 [8192,512] @ Wall^T [1536,512].  n in [0,512)=q, [512,1024)=k, [1024,1536)=v.
__global__ __launch_bounds__(256) void qkv_kernel(const unsigned short* __restrict__ xb,
                                                  const unsigned short* __restrict__ wb,
                                                  const float* __restrict__ bq,
                                                  const float* __restrict__ bk,
                                                  const float* __restrict__ bv,
                                                  const float2* __restrict__ tab,
                                                  unsigned short* __restrict__ qrot,
                                                  unsigned short* __restrict__ krot,
                                                  unsigned short* __restrict__ vt) {
  __shared__ __align__(16) unsigned short sA[128 * 64];
  __shared__ __align__(16) unsigned short sB[128 * 64];
  int t = threadIdx.x, w = t >> 6, l = t & 63, wr = w >> 1, wc = w & 1;
  int m0 = blockIdx.x * 128, n0 = blockIdx.y * 128;
  f32x4 acc[4][4] = {};
  for (int k0 = 0; k0 < 512; k0 += 64) {
    stage128x64(xb + (size_t)m0 * 512 + k0, 512, sA, t);
    stage128x64(wb + (size_t)n0 * 512 + k0, 512, sB, t);
    __syncthreads();
    mfma_step64(sA, sB, wr, wc, l, acc);
    __syncthreads();
  }
  int sec = n0 >> 9;  // 0=q 1=k 2=v (tiles never straddle sections: 512%128==0)
  const float* bias = (sec == 0) ? bq : (sec == 1) ? bk : bv;
  unsigned short* qk_dst = (sec == 0) ? qrot : krot;
  int col_l = l & 15, rgrp = (l >> 4) << 2;
#pragma unroll
  for (int n = 0; n < 4; ++n) {
    int eg = n0 + wc * 64 + n * 16 + col_l;
    int e  = eg & 511;
    float bsv = bias[e];
    if (sec < 2) {
      int i = e >> 1;
#pragma unroll
      for (int m = 0; m < 4; ++m) {
        int rowb = m0 + wr * 64 + m * 16 + rgrp;
#pragma unroll
        for (int r = 0; r < 4; ++r) {
          int mg = rowb + r;
          int cpos = mg & (CTXN - 1);
          float val  = acc[m][n][r] + bsv;
          float part = __shfl_xor(val, 1);
          float2 cs  = tab[cpos * 256 + i];
          float o = (e & 1) ? fmaf(part, cs.y, val * cs.x)    //  q2i*sin + q2i1*cos
                            : fmaf(-part, cs.y, val * cs.x);  //  q2i*cos - q2i1*sin
          qk_dst[(size_t)mg * 512 + e] = f2bf(o);
        }
      }
    } else {
#pragma unroll
      for (int m = 0; m < 4; ++m) {
        int rowb = m0 + wr * 64 + m * 16 + rgrp;
        int bidx = rowb >> 10;
        int cpos = rowb & (CTXN - 1);
        ushort4 pk;
        pk.x = f2bf(acc[m][n][0] + bsv);
        pk.y = f2bf(acc[m][n][1] + bsv);
        pk.z = f2bf(acc[m][n][2] + bsv);
        pk.w = f2bf(acc[m][n][3] + bsv);
        *(ushort4*)(vt + ((size_t)bidx * 512 + e) * 1024 + cpos) = pk;  // vt[b][d][c]
      }
    }
  }
}

// ---------------- K3: scores = qrot @ krot^T * scale (triangular tiles) ----------------
__global__ __launch_bounds__(256) void scores_kernel(const unsigned short* __restrict__ qr,
                                                     const unsigned short* __restrict__ kr,
                                                     float* __restrict__ S) {
  int it = blockIdx.x, jt = blockIdx.y, b = blockIdx.z;
  if (jt > it) return;
  __shared__ __align__(16) unsigned short sA[128 * 64];
  __shared__ __align__(16) unsigned short sB[128 * 64];
  int t = threadIdx.x, w = t >> 6, l = t & 63, wr = w >> 1, wc = w & 1;
  const unsigned short* A  = qr + ((size_t)b << 19) + (size_t)it * 128 * 512;
  const unsigned short* Bp = kr + ((size_t)b << 19) + (size_t)jt * 128 * 512;
  f32x4 acc[4][4] = {};
  for (int k0 = 0; k0 < 512; k0 += 64) {
    stage128x64(A + k0, 512, sA, t);
    stage128x64(Bp + k0, 512, sB, t);
    __syncthreads();
    mfma_step64(sA, sB, wr, wc, l, acc);
    __syncthreads();
  }
  const float scale = 0.04419417382415922f;  // 1/sqrt(512)
  float* Sb = S + ((size_t)b << 20);
  int col_l = l & 15, rgrp = (l >> 4) << 2;
#pragma unroll
  for (int m = 0; m < 4; ++m) {
    int iq = it * 128 + wr * 64 + m * 16 + rgrp;
#pragma unroll
    for (int n = 0; n < 4; ++n) {
      int j = jt * 128 + wc * 64 + n * 16 + col_l;
#pragma unroll
      for (int r = 0; r < 4; ++r)
        Sb[(size_t)(iq + r) * 1024 + j] = acc[m][n][r] * scale;
    }
  }
}

// ---------------- K4: causal row softmax, single pass, one wave per row ----------------
__global__ __launch_bounds__(256) void softmax_kernel(const float* __restrict__ S,
                                                      unsigned short* __restrict__ P) {
  int w = threadIdx.x >> 6, l = threadIdx.x & 63;
  int i = blockIdx.x * 4 + w;              // row 0..1023
  int b = blockIdx.y;
  const float* row = S + ((size_t)b << 20) + (size_t)i * 1024;
  unsigned short* prow = P + ((size_t)b << 20) + (size_t)i * 1024;
  int len  = i + 1;
  int jmax = ((i >> 7) + 1) << 7;          // zero-fill to end of diagonal 128-tile
  float v[16];
  float mx = -3.4e38f;
#pragma unroll
  for (int p = 0; p < 16; ++p) {
    int j = l + (p << 6);
    v[p] = (j < len) ? row[j] : -3.4e38f;
    mx = fmaxf(mx, v[p]);
  }
#pragma unroll
  for (int o = 32; o > 0; o >>= 1) mx = fmaxf(mx, __shfl_xor(mx, o));
  float sm = 0.0f;
#pragma unroll
  for (int p = 0; p < 16; ++p) {
    int j = l + (p << 6);
    v[p] = (j < len) ? __expf(v[p] - mx) : 0.0f;
    sm += v[p];
  }
#pragma unroll
  for (int o = 32; o > 0; o >>= 1) sm += __shfl_xor(sm, o);
  float inv = 1.0f / sm;
#pragma unroll
  for (int p = 0; p < 16; ++p) {
    int j = l + (p << 6);
    if (j < jmax) prow[j] = f2bf(v[p] * inv);
  }
}

// ---------------- K5: out = P @ V  (A=P [1024,1024] bf16, B=vt [512,1024] = V^T) ----------------
__global__ __launch_bounds__(256) void pv_kernel(const unsigned short* __restrict__ P,
                                                 const unsigned short* __restrict__ vt,
                                                 float* __restrict__ out) {
  int it = blockIdx.x, nt = blockIdx.y, b = blockIdx.z;
  __shared__ __align__(16) unsigned short sA[128 * 64];
  __shared__ __align__(16) unsigned short sB[128 * 64];
  int t = threadIdx.x, w = t >> 6, l = t & 63, wr = w >> 1, wc = w & 1;
  const unsigned short* A  = P  + ((size_t)b << 20) + (size_t)it * 128 * 1024;
  const unsigned short* Bp = vt + ((size_t)b << 19) + (size_t)nt * 128 * 1024;
  int kend = (it + 1) << 7;  // causal: j < (it+1)*128
  f32x4 acc[4][4] = {};
  for (int k0 = 0; k0 < kend; k0 += 64) {
    stage128x64(A + k0, 1024, sA, t);
    stage128x64(Bp + k0, 1024, sB, t);
    __syncthreads();
    mfma_step64(sA, sB, wr, wc, l, acc);
    __syncthreads();
  }
  float* ob = out + ((size_t)b << 19);
  int col_l = l & 15, rgrp = (l >> 4) << 2;
#pragma unroll
  for (int m = 0; m < 4; ++m) {
    int iq = it * 128 + wr * 64 + m * 16 + rgrp;
#pragma unroll
    for (int n = 0; n < 4; ++n) {
      int d = nt * 128 + wc * 64 + n * 16 + col_l;
#pragma unroll
      for (int r = 0; r < 4; ++r)
        ob[(size_t)(iq + r) * 512 + d] = acc[m][n][r];
    }
  }
}

// ---------------- launch ----------------
extern "C" void kernel_launch(void* const* d_in, const int* in_sizes, int n_in,
                              void* d_out, int out_size, void* d_ws, size_t ws_size,
                              hipStream_t stream) {
  const float* x  = (const float*)d_in[0];
  const float* wq = (const float*)d_in[1];
  const float* bq = (const float*)d_in[2];
  const float* wk = (const float*)d_in[3];
  const float* bk = (const float*)d_in[4];
  const float* wv = (const float*)d_in[5];
  const float* bv = (const float*)d_in[6];
  float* out = (float*)d_out;

  char* ws = (char*)d_ws;
  float2*         tab  = (float2*)(ws);                          //  2 MB
  unsigned short* xb   = (unsigned short*)(ws + (2ull  << 20));  //  8 MB
  unsigned short* wb   = (unsigned short*)(ws + (10ull << 20));  //  1.5 MB
  unsigned short* qrot = (unsigned short*)(ws + (12ull << 20));  //  8 MB
  unsigned short* krot = (unsigned short*)(ws + (20ull << 20));  //  8 MB
  unsigned short* vt   = (unsigned short*)(ws + (28ull << 20));  //  8 MB
  float*          S    = (float*)(ws + (36ull << 20));           // 32 MB
  unsigned short* P    = (unsigned short*)(ws + (68ull << 20));  // 16 MB -> total 84 MB

  // prep (2 launches)
  prep_table<<<dim3(CTXN), dim3(256), 0, stream>>>(tab);
  prep_cast_all<<<dim3(4864), dim3(256), 0, stream>>>(x, wq, wk, wv, xb, wb);

  // QKV + RoPE
  qkv_kernel<<<dim3(64, 12), dim3(256), 0, stream>>>(xb, wb, bq, bk, bv, tab, qrot, krot, vt);

  // scores (lower-triangular tiles only)
  scores_kernel<<<dim3(8, 8, BATCH), dim3(256), 0, stream>>>(qrot, krot, S);

  // causal softmax (single pass, 1 wave/row)
  softmax_kernel<<<dim3(256, BATCH), dim3(256), 0, stream>>>(S, P);

  // PV
  pv_kernel<<<dim3(8, 4, BATCH), dim3(256), 0, stream>>>(P, vt, out);
}

// Round 3
// 84.223 us; speedup vs baseline: 1.4236x; 1.1764x over previous
//
#include <hip/hip_runtime.h>

// Problem: B=8, CTX=1024, D=512 RoPE attention head, fp32 in/out, bf16-tolerance.
#define BATCH 8
#define CTXN  1024
#define DMODEL 512

using short8 = __attribute__((ext_vector_type(8))) short;
using f32x4  = __attribute__((ext_vector_type(4))) float;

typedef const void __attribute__((address_space(1)))* as1_cvp;
typedef void __attribute__((address_space(3)))* as3_vp;

__device__ __forceinline__ unsigned short f2bf(float f) {
  unsigned int u = __float_as_uint(f);
  u += 0x7fffu + ((u >> 16) & 1u);   // round-to-nearest-even
  return (unsigned short)(u >> 16);
}
__device__ __forceinline__ float bf2f(unsigned short u) {
  return __uint_as_float((unsigned int)u << 16);
}

// ---------------- prep kernels ----------------

__global__ __launch_bounds__(256) void prep_table(float2* __restrict__ tab) {
  int c = blockIdx.x;          // 1024
  int i = threadIdx.x;         // 256 = D/2
  float freq = exp2f((float)i * (-13.287712379549449f / 256.0f));  // 10000^(-i/256)
  float th = (float)c * freq;
  float sn, cs;
  sincosf(th, &sn, &cs);
  tab[c * 256 + i] = make_float2(cs, sn);
}

#define X4  1048576   // 8*1024*512/4
#define W4  65536     // 512*512/4
__global__ __launch_bounds__(256) void prep_cast_all(const float* __restrict__ x,
                                                     const float* __restrict__ wq,
                                                     const float* __restrict__ wk,
                                                     const float* __restrict__ wv,
                                                     unsigned short* __restrict__ xb,
                                                     unsigned short* __restrict__ wb) {
  int gid = blockIdx.x * 256 + threadIdx.x;
  const float4* src; ushort4* dst;
  if (gid < X4)                { src = (const float4*)x  + gid;              dst = (ushort4*)xb + gid; }
  else if (gid < X4 + W4)      { int o = gid - X4;       src = (const float4*)wq + o; dst = (ushort4*)wb + o; }
  else if (gid < X4 + 2 * W4)  { int o = gid - X4 - W4;  src = (const float4*)wk + o; dst = (ushort4*)(wb + 262144) + o; }
  else                         { int o = gid - X4 - 2*W4; src = (const float4*)wv + o; dst = (ushort4*)(wb + 524288) + o; }
  float4 f = *src;
  ushort4 u;
  u.x = f2bf(f.x); u.y = f2bf(f.y); u.z = f2bf(f.z); u.w = f2bf(f.w);
  *dst = u;
}

// ---------------- GEMM core: 128x128 tile, BK=64, dbuf + counted vmcnt + swizzle ----------------
// LDS tile layout: [128 rows][64 k-elems] bf16, 16 KB per slot, 2 slots per operand.
// Swizzle (involution): 16B-chunk index ch' = ch ^ (row & 7). Applied on the GLOBAL
// source of global_load_lds (LDS dest lane-linear, required by HW) and on ds_reads.

__device__ __forceinline__ void issue_tile(const unsigned short* __restrict__ gA, int ldA,
                                           const unsigned short* __restrict__ gB, int ldB,
                                           unsigned short* sA, unsigned short* sB,
                                           int slot, int tid) {
  unsigned short* dA = sA + (slot << 13);
  unsigned short* dB = sB + (slot << 13);
#pragma unroll
  for (int c = 0; c < 4; ++c) {
    int li  = (c << 8) + tid;            // 0..1023 16B-chunks
    int row = li >> 3;
    int ch  = (li & 7) ^ (row & 7);      // pre-swizzled global chunk
    __builtin_amdgcn_global_load_lds((as1_cvp)(gA + (size_t)row * ldA + (ch << 3)),
                                     (as3_vp)(dA + (li << 3)), 16, 0, 0);
  }
#pragma unroll
  for (int c = 0; c < 4; ++c) {
    int li  = (c << 8) + tid;
    int row = li >> 3;
    int ch  = (li & 7) ^ (row & 7);
    __builtin_amdgcn_global_load_lds((as1_cvp)(gB + (size_t)row * ldB + (ch << 3)),
                                     (as3_vp)(dB + (li << 3)), 16, 0, 0);
  }
}

// Fills acc[4][4] for this thread's wave (wave grid 2x2, per-wave 64x64 output).
__device__ __forceinline__ void gemm_pipe(const unsigned short* __restrict__ gA, int ldA,
                                          const unsigned short* __restrict__ gB, int ldB,
                                          int nt, unsigned short* sA, unsigned short* sB,
                                          int tid, f32x4 acc[4][4]) {
  const int l = tid & 63, w = tid >> 6, wr = w >> 1, wc = w & 1;
  const int rl = l & 15, kq = l >> 4;   // kq in 0..3
  int aoff[4][2], boff[4][2];
#pragma unroll
  for (int m = 0; m < 4; ++m) {
    int ra = wr * 64 + m * 16 + rl;
    int rb = wc * 64 + m * 16 + rl;
#pragma unroll
    for (int ks = 0; ks < 2; ++ks) {
      int kc = ks * 4 + kq;
      aoff[m][ks] = ra * 64 + (((kc ^ (ra & 7))) << 3);
      boff[m][ks] = rb * 64 + (((kc ^ (rb & 7))) << 3);
    }
  }
  // prologue: stage tiles 0,1 ; wait tile0 ; barrier
  issue_tile(gA, ldA, gB, ldB, sA, sB, 0, tid);
  issue_tile(gA + 64, ldA, gB + 64, ldB, sA, sB, 1, tid);
  asm volatile("s_waitcnt vmcnt(8)" ::: "memory");
  __builtin_amdgcn_s_barrier();
  __builtin_amdgcn_sched_barrier(0);

  for (int t = 0; t < nt; ++t) {
    const unsigned short* sAb = sA + ((t & 1) << 13);
    const unsigned short* sBb = sB + ((t & 1) << 13);
    short8 af[4][2], bf0[2][2], bf1[2][2];
    // ---- phase A: all A-frags + B-frags n=0,1 ; MFMA n01 ----
#pragma unroll
    for (int m = 0; m < 4; ++m)
#pragma unroll
      for (int ks = 0; ks < 2; ++ks)
        af[m][ks] = *(const short8*)(sAb + aoff[m][ks]);
#pragma unroll
    for (int n = 0; n < 2; ++n)
#pragma unroll
      for (int ks = 0; ks < 2; ++ks)
        bf0[n][ks] = *(const short8*)(sBb + boff[n][ks]);
    __builtin_amdgcn_s_setprio(1);
#pragma unroll
    for (int ks = 0; ks < 2; ++ks)
#pragma unroll
      for (int m = 0; m < 4; ++m)
#pragma unroll
        for (int n = 0; n < 2; ++n)
          acc[m][n] = __builtin_amdgcn_mfma_f32_16x16x32_bf16(af[m][ks], bf0[n][ks], acc[m][n], 0, 0, 0);
    __builtin_amdgcn_s_setprio(0);
    // ---- phase B: B-frags n=2,3 ; fence reads ; barrier ; prefetch t+2 ; counted vmcnt ; MFMA n23 ----
#pragma unroll
    for (int n = 0; n < 2; ++n)
#pragma unroll
      for (int ks = 0; ks < 2; ++ks)
        bf1[n][ks] = *(const short8*)(sBb + boff[n + 2][ks]);
    asm volatile("s_waitcnt lgkmcnt(0)" ::: "memory");   // all my slot reads done (pins loads above)
    __builtin_amdgcn_s_barrier();                        // all waves' slot reads done
    __builtin_amdgcn_sched_barrier(0);
    if (t + 2 < nt) {
      issue_tile(gA + (size_t)(t + 2) * 64, ldA, gB + (size_t)(t + 2) * 64, ldB, sA, sB, t & 1, tid);
      asm volatile("s_waitcnt vmcnt(8)" ::: "memory");   // tile t+1 landed; t+2 stays in flight
    } else {
      asm volatile("s_waitcnt vmcnt(0)" ::: "memory");   // epilogue drain
    }
    __builtin_amdgcn_sched_barrier(0);
    __builtin_amdgcn_s_setprio(1);
#pragma unroll
    for (int ks = 0; ks < 2; ++ks)
#pragma unroll
      for (int m = 0; m < 4; ++m)
#pragma unroll
        for (int n = 0; n < 2; ++n)
          acc[m][n + 2] = __builtin_amdgcn_mfma_f32_16x16x32_bf16(af[m][ks], bf1[n][ks], acc[m][n + 2], 0, 0, 0);
    __builtin_amdgcn_s_setprio(0);
    __builtin_amdgcn_s_barrier();                        // tile t+1 visible to all before next reads
    __builtin_amdgcn_sched_barrier(0);
  }
}

// ---------------- K2: QKV projection + bias + RoPE, V transposed ----------------
__global__ __launch_bounds__(256) void qkv_kernel(const unsigned short* __restrict__ xb,
                                                  const unsigned short* __restrict__ wb,
                                                  const float* __restrict__ bq,
                                                  const float* __restrict__ bk,
                                                  const float* __restrict__ bv,
                                                  const float2* __restrict__ tab,
                                                  unsigned short* __restrict__ qrot,
                                                  unsigned short* __restrict__ krot,
                                                  unsigned short* __restrict__ vt) {
  __shared__ __align__(16) unsigned short sA[2 * 8192];
  __shared__ __align__(16) unsigned short sB[2 * 8192];
  int t = threadIdx.x, w = t >> 6, l = t & 63, wr = w >> 1, wc = w & 1;
  int m0 = blockIdx.x * 128, n0 = blockIdx.y * 128;
  f32x4 acc[4][4] = {};
  gemm_pipe(xb + (size_t)m0 * 512, 512, wb + (size_t)n0 * 512, 512, 8, sA, sB, t, acc);

  int sec = n0 >> 9;  // 0=q 1=k 2=v
  const float* bias = (sec == 0) ? bq : (sec == 1) ? bk : bv;
  unsigned short* qk_dst = (sec == 0) ? qrot : krot;
  int col_l = l & 15, rgrp = (l >> 4) << 2;
#pragma unroll
  for (int n = 0; n < 4; ++n) {
    int eg = n0 + wc * 64 + n * 16 + col_l;
    int e  = eg & 511;
    float bsv = bias[e];
    if (sec < 2) {
      int i = e >> 1;
#pragma unroll
      for (int m = 0; m < 4; ++m) {
        int rowb = m0 + wr * 64 + m * 16 + rgrp;
#pragma unroll
        for (int r = 0; r < 4; ++r) {
          int mg = rowb + r;
          int cpos = mg & (CTXN - 1);
          float val  = acc[m][n][r] + bsv;
          float part = __shfl_xor(val, 1);
          float2 cs  = tab[cpos * 256 + i];
          float o = (e & 1) ? fmaf(part, cs.y, val * cs.x)
                            : fmaf(-part, cs.y, val * cs.x);
          qk_dst[(size_t)mg * 512 + e] = f2bf(o);
        }
      }
    } else {
#pragma unroll
      for (int m = 0; m < 4; ++m) {
        int rowb = m0 + wr * 64 + m * 16 + rgrp;
        int bidx = rowb >> 10;
        int cpos = rowb & (CTXN - 1);
        ushort4 pk;
        pk.x = f2bf(acc[m][n][0] + bsv);
        pk.y = f2bf(acc[m][n][1] + bsv);
        pk.z = f2bf(acc[m][n][2] + bsv);
        pk.w = f2bf(acc[m][n][3] + bsv);
        *(ushort4*)(vt + ((size_t)bidx * 512 + e) * 1024 + cpos) = pk;  // vt[b][d][c]
      }
    }
  }
}

// ---------------- K3: scores = qrot @ krot^T * scale -> bf16 S (triangular tiles) ----------------
__global__ __launch_bounds__(256) void scores_kernel(const unsigned short* __restrict__ qr,
                                                     const unsigned short* __restrict__ kr,
                                                     unsigned short* __restrict__ S) {
  int it = blockIdx.x, jt = blockIdx.y, b = blockIdx.z;
  if (jt > it) return;
  __shared__ __align__(16) unsigned short sA[2 * 8192];
  __shared__ __align__(16) unsigned short sB[2 * 8192];
  int t = threadIdx.x, w = t >> 6, l = t & 63, wr = w >> 1, wc = w & 1;
  const unsigned short* A  = qr + ((size_t)b << 19) + (size_t)it * 128 * 512;
  const unsigned short* Bp = kr + ((size_t)b << 19) + (size_t)jt * 128 * 512;
  f32x4 acc[4][4] = {};
  gemm_pipe(A, 512, Bp, 512, 8, sA, sB, t, acc);

  const float scale = 0.04419417382415922f;  // 1/sqrt(512)
  unsigned short* Sb = S + ((size_t)b << 20);
  int col_l = l & 15, rgrp = (l >> 4) << 2;
#pragma unroll
  for (int m = 0; m < 4; ++m) {
    int iq = it * 128 + wr * 64 + m * 16 + rgrp;
#pragma unroll
    for (int n = 0; n < 4; ++n) {
      int j = jt * 128 + wc * 64 + n * 16 + col_l;
#pragma unroll
      for (int r = 0; r < 4; ++r)
        Sb[(size_t)(iq + r) * 1024 + j] = f2bf(acc[m][n][r] * scale);
    }
  }
}

// ---------------- K4: causal row softmax (bf16 in), single pass, one wave per row ----------------
__global__ __launch_bounds__(256) void softmax_kernel(const unsigned short* __restrict__ S,
                                                      unsigned short* __restrict__ P) {
  int w = threadIdx.x >> 6, l = threadIdx.x & 63;
  int i = blockIdx.x * 4 + w;              // row 0..1023
  int b = blockIdx.y;
  const unsigned short* row = S + ((size_t)b << 20) + (size_t)i * 1024;
  unsigned short* prow = P + ((size_t)b << 20) + (size_t)i * 1024;
  int len  = i + 1;
  int jmax = ((i >> 7) + 1) << 7;          // zero-fill to end of diagonal 128-tile
  float v[16];
  float mx = -3.4e38f;
#pragma unroll
  for (int p = 0; p < 16; ++p) {
    int j = l + (p << 6);
    v[p] = (j < len) ? bf2f(row[j]) : -3.4e38f;
    mx = fmaxf(mx, v[p]);
  }
#pragma unroll
  for (int o = 32; o > 0; o >>= 1) mx = fmaxf(mx, __shfl_xor(mx, o));
  float sm = 0.0f;
#pragma unroll
  for (int p = 0; p < 16; ++p) {
    int j = l + (p << 6);
    v[p] = (j < len) ? __expf(v[p] - mx) : 0.0f;
    sm += v[p];
  }
#pragma unroll
  for (int o = 32; o > 0; o >>= 1) sm += __shfl_xor(sm, o);
  float inv = 1.0f / sm;
#pragma unroll
  for (int p = 0; p < 16; ++p) {
    int j = l + (p << 6);
    if (j < jmax) prow[j] = f2bf(v[p] * inv);
  }
}

// ---------------- K5: out = P @ V  (A=P [1024,1024] bf16, B=vt = V^T [512,1024]) ----------------
__global__ __launch_bounds__(256) void pv_kernel(const unsigned short* __restrict__ P,
                                                 const unsigned short* __restrict__ vt,
                                                 float* __restrict__ out) {
  int it = blockIdx.x, nt2 = blockIdx.y, b = blockIdx.z;
  __shared__ __align__(16) unsigned short sA[2 * 8192];
  __shared__ __align__(16) unsigned short sB[2 * 8192];
  int t = threadIdx.x, w = t >> 6, l = t & 63, wr = w >> 1, wc = w & 1;
  const unsigned short* A  = P  + ((size_t)b << 20) + (size_t)it * 128 * 1024;
  const unsigned short* Bp = vt + ((size_t)b << 19) + (size_t)nt2 * 128 * 1024;
  int nt = (it + 1) * 2;   // causal: K-tiles of 64 up to (it+1)*128
  f32x4 acc[4][4] = {};
  gemm_pipe(A, 1024, Bp, 1024, nt, sA, sB, t, acc);

  float* ob = out + ((size_t)b << 19);
  int col_l = l & 15, rgrp = (l >> 4) << 2;
#pragma unroll
  for (int m = 0; m < 4; ++m) {
    int iq = it * 128 + wr * 64 + m * 16 + rgrp;
#pragma unroll
    for (int n = 0; n < 4; ++n) {
      int d = nt2 * 128 + wc * 64 + n * 16 + col_l;
#pragma unroll
      for (int r = 0; r < 4; ++r)
        ob[(size_t)(iq + r) * 512 + d] = acc[m][n][r];
    }
  }
}

// ---------------- launch ----------------
extern "C" void kernel_launch(void* const* d_in, const int* in_sizes, int n_in,
                              void* d_out, int out_size, void* d_ws, size_t ws_size,
                              hipStream_t stream) {
  const float* x  = (const float*)d_in[0];
  const float* wq = (const float*)d_in[1];
  const float* bq = (const float*)d_in[2];
  const float* wk = (const float*)d_in[3];
  const float* bk = (const float*)d_in[4];
  const float* wv = (const float*)d_in[5];
  const float* bv = (const float*)d_in[6];
  float* out = (float*)d_out;

  char* ws = (char*)d_ws;
  float2*         tab  = (float2*)(ws);                          //  2 MB
  unsigned short* xb   = (unsigned short*)(ws + (2ull  << 20));  //  8 MB
  unsigned short* wb   = (unsigned short*)(ws + (10ull << 20));  //  1.5 MB
  unsigned short* qrot = (unsigned short*)(ws + (12ull << 20));  //  8 MB
  unsigned short* krot = (unsigned short*)(ws + (20ull << 20));  //  8 MB
  unsigned short* vt   = (unsigned short*)(ws + (28ull << 20));  //  8 MB
  unsigned short* S    = (unsigned short*)(ws + (36ull << 20));  // 16 MB (bf16 now)
  unsigned short* P    = (unsigned short*)(ws + (52ull << 20));  // 16 MB -> total 68 MB

  prep_table<<<dim3(CTXN), dim3(256), 0, stream>>>(tab);
  prep_cast_all<<<dim3(4864), dim3(256), 0, stream>>>(x, wq, wk, wv, xb, wb);

  qkv_kernel<<<dim3(64, 12), dim3(256), 0, stream>>>(xb, wb, bq, bk, bv, tab, qrot, krot, vt);
  scores_kernel<<<dim3(8, 8, BATCH), dim3(256), 0, stream>>>(qrot, krot, S);
  softmax_kernel<<<dim3(256, BATCH), dim3(256), 0, stream>>>(S, P);
  pv_kernel<<<dim3(8, 4, BATCH), dim3(256), 0, stream>>>(P, vt, out);
}

// Round 4
// 77.680 us; speedup vs baseline: 1.5435x; 1.0842x over previous
//
#include <hip/hip_runtime.h>

// Problem: B=8, CTX=1024, D=512 RoPE attention head, fp32 in/out, bf16-tolerance.
#define BATCH 8
#define CTXN  1024
#define DMODEL 512

using short8  = __attribute__((ext_vector_type(8))) short;
using f32x16  = __attribute__((ext_vector_type(16))) float;

typedef const void __attribute__((address_space(1)))* as1_cvp;
typedef void __attribute__((address_space(3)))* as3_vp;

__device__ __forceinline__ unsigned short f2bf(float f) {
  unsigned int u = __float_as_uint(f);
  u += 0x7fffu + ((u >> 16) & 1u);   // round-to-nearest-even
  return (unsigned short)(u >> 16);
}
__device__ __forceinline__ float bf2f(unsigned short u) {
  return __uint_as_float((unsigned int)u << 16);
}

// ---------------- fused prep: bf16 casts + RoPE cos/sin table, one launch ----------------
#define X4  1048576   // 8*1024*512/4
#define W4  65536     // 512*512/4
#define CAST_BLOCKS 4864   // (X4+3*W4)/256
__global__ __launch_bounds__(256) void prep_all(const float* __restrict__ x,
                                                const float* __restrict__ wq,
                                                const float* __restrict__ wk,
                                                const float* __restrict__ wv,
                                                unsigned short* __restrict__ xb,
                                                unsigned short* __restrict__ wb,
                                                float2* __restrict__ tab) {
  if (blockIdx.x < CAST_BLOCKS) {
    int gid = blockIdx.x * 256 + threadIdx.x;
    const float4* src; ushort4* dst;
    if (gid < X4)                { src = (const float4*)x  + gid;              dst = (ushort4*)xb + gid; }
    else if (gid < X4 + W4)      { int o = gid - X4;        src = (const float4*)wq + o; dst = (ushort4*)wb + o; }
    else if (gid < X4 + 2 * W4)  { int o = gid - X4 - W4;   src = (const float4*)wk + o; dst = (ushort4*)(wb + 262144) + o; }
    else                         { int o = gid - X4 - 2*W4; src = (const float4*)wv + o; dst = (ushort4*)(wb + 524288) + o; }
    float4 f = *src;
    ushort4 u;
    u.x = f2bf(f.x); u.y = f2bf(f.y); u.z = f2bf(f.z); u.w = f2bf(f.w);
    *dst = u;
  } else {
    int c = blockIdx.x - CAST_BLOCKS;   // 0..1023
    int i = threadIdx.x;                // 0..255 = D/2
    float freq = exp2f((float)i * (-13.287712379549449f / 256.0f));  // 10000^(-i/256)
    float th = (float)c * freq;
    float sn, cs;
    sincosf(th, &sn, &cs);
    tab[c * 256 + i] = make_float2(cs, sn);
  }
}

// ---------------- GEMM core: 128x128 tile, BK=64, 32x32x16 MFMA, dbuf+counted vmcnt+swizzle ----
// LDS tile: [128 rows][64 k] bf16, 16 KB/slot, 2 slots per operand (64 KB total).
// Swizzle (involution): 16B-chunk ch' = ch ^ (row & 7), applied on the GLOBAL source of
// global_load_lds (LDS dest lane-linear, HW requirement) and on ds_read addresses.

__device__ __forceinline__ void issue_tile(const unsigned short* __restrict__ gA, int ldA,
                                           const unsigned short* __restrict__ gB, int ldB,
                                           unsigned short* sA, unsigned short* sB,
                                           int slot, int tid) {
  unsigned short* dA = sA + (slot << 13);
  unsigned short* dB = sB + (slot << 13);
#pragma unroll
  for (int c = 0; c < 4; ++c) {
    int li  = (c << 8) + tid;            // 0..1023 16B-chunks
    int row = li >> 3;
    int ch  = (li & 7) ^ (row & 7);
    __builtin_amdgcn_global_load_lds((as1_cvp)(gA + (size_t)row * ldA + (ch << 3)),
                                     (as3_vp)(dA + (li << 3)), 16, 0, 0);
  }
#pragma unroll
  for (int c = 0; c < 4; ++c) {
    int li  = (c << 8) + tid;
    int row = li >> 3;
    int ch  = (li & 7) ^ (row & 7);
    __builtin_amdgcn_global_load_lds((as1_cvp)(gB + (size_t)row * ldB + (ch << 3)),
                                     (as3_vp)(dB + (li << 3)), 16, 0, 0);
  }
}

// 4 waves, wave grid 2x2, per-wave 64x64 output = 2x2 frags of 32x32 (f32x16 each).
__device__ __forceinline__ void gemm_pipe(const unsigned short* __restrict__ gA, int ldA,
                                          const unsigned short* __restrict__ gB, int ldB,
                                          int nt, unsigned short* sA, unsigned short* sB,
                                          int tid, f32x16 acc[2][2]) {
  const int l = tid & 63, w = tid >> 6, wr = w >> 1, wc = w & 1;
  const int cl = l & 31, hi = l >> 5;
  int aoff[2][4], boff[2][4];
#pragma unroll
  for (int m = 0; m < 2; ++m) {
    int ra = wr * 64 + m * 32 + cl;
    int rb = wc * 64 + m * 32 + cl;
#pragma unroll
    for (int ks = 0; ks < 4; ++ks) {
      int kc = ks * 2 + hi;              // 16B chunk within 64-elem row
      aoff[m][ks] = ra * 64 + ((kc ^ (ra & 7)) << 3);
      boff[m][ks] = rb * 64 + ((kc ^ (rb & 7)) << 3);
    }
  }
  // prologue: stage tiles 0,1 ; wait tile0 ; barrier
  issue_tile(gA, ldA, gB, ldB, sA, sB, 0, tid);
  issue_tile(gA + 64, ldA, gB + 64, ldB, sA, sB, 1, tid);
  asm volatile("s_waitcnt vmcnt(8)" ::: "memory");
  __builtin_amdgcn_s_barrier();
  __builtin_amdgcn_sched_barrier(0);

  for (int t = 0; t < nt; ++t) {
    const unsigned short* sAb = sA + ((t & 1) << 13);
    const unsigned short* sBb = sB + ((t & 1) << 13);
    short8 af[2][4], bfv[2][4];
#pragma unroll
    for (int m = 0; m < 2; ++m)
#pragma unroll
      for (int ks = 0; ks < 4; ++ks)
        af[m][ks] = *(const short8*)(sAb + aoff[m][ks]);
#pragma unroll
    for (int n = 0; n < 2; ++n)
#pragma unroll
      for (int ks = 0; ks < 4; ++ks)
        bfv[n][ks] = *(const short8*)(sBb + boff[n][ks]);
    asm volatile("s_waitcnt lgkmcnt(0)" ::: "memory");   // my slot reads done
    __builtin_amdgcn_sched_barrier(0);
    __builtin_amdgcn_s_barrier();                        // all waves' reads done -> slot free
    if (t + 2 < nt) {
      issue_tile(gA + (size_t)(t + 2) * 64, ldA, gB + (size_t)(t + 2) * 64, ldB, sA, sB, t & 1, tid);
      asm volatile("s_waitcnt vmcnt(8)" ::: "memory");   // tile t+1 landed; t+2 in flight
    } else {
      asm volatile("s_waitcnt vmcnt(0)" ::: "memory");   // epilogue drain
    }
    __builtin_amdgcn_sched_barrier(0);
    __builtin_amdgcn_s_setprio(1);
#pragma unroll
    for (int ks = 0; ks < 4; ++ks)
#pragma unroll
      for (int m = 0; m < 2; ++m)
#pragma unroll
        for (int n = 0; n < 2; ++n)
          acc[m][n] = __builtin_amdgcn_mfma_f32_32x32x16_bf16(af[m][ks], bfv[n][ks], acc[m][n], 0, 0, 0);
    __builtin_amdgcn_s_setprio(0);
    __builtin_amdgcn_s_barrier();                        // tile t+1 visible before next reads
    __builtin_amdgcn_sched_barrier(0);
  }
}

// C/D mapping (m74/m101): col = lane&31, row = (reg&3) + 8*(reg>>2) + 4*(lane>>5).

// ---------------- K2: QKV projection + bias + RoPE, V transposed ----------------
__global__ __launch_bounds__(256) void qkv_kernel(const unsigned short* __restrict__ xb,
                                                  const unsigned short* __restrict__ wb,
                                                  const float* __restrict__ bq,
                                                  const float* __restrict__ bk,
                                                  const float* __restrict__ bv,
                                                  const float2* __restrict__ tab,
                                                  unsigned short* __restrict__ qrot,
                                                  unsigned short* __restrict__ krot,
                                                  unsigned short* __restrict__ vt) {
  __shared__ __align__(16) unsigned short sA[2 * 8192];
  __shared__ __align__(16) unsigned short sB[2 * 8192];
  int t = threadIdx.x, w = t >> 6, l = t & 63, wr = w >> 1, wc = w & 1;
  int cl = l & 31, hi = l >> 5;
  int m0 = blockIdx.x * 128, n0 = blockIdx.y * 128;
  f32x16 acc[2][2] = {};
  gemm_pipe(xb + (size_t)m0 * 512, 512, wb + (size_t)n0 * 512, 512, 8, sA, sB, t, acc);

  int sec = n0 >> 9;  // 0=q 1=k 2=v (tiles never straddle: 512%128==0)
  const float* bias = (sec == 0) ? bq : (sec == 1) ? bk : bv;
  unsigned short* qk_dst = (sec == 0) ? qrot : krot;
#pragma unroll
  for (int n = 0; n < 2; ++n) {
    int eg = n0 + wc * 64 + n * 32 + cl;
    int e  = eg & 511;
    float bsv = bias[e];
    if (sec < 2) {
      int i2 = e >> 1;
#pragma unroll
      for (int m = 0; m < 2; ++m) {
        int rowb = m0 + wr * 64 + m * 32 + 4 * hi;
#pragma unroll
        for (int r = 0; r < 16; ++r) {
          int mg = rowb + (r & 3) + 8 * (r >> 2);
          int cpos = mg & (CTXN - 1);
          float val  = acc[m][n][r] + bsv;
          float part = __shfl_xor(val, 1);
          float2 cs  = tab[cpos * 256 + i2];
          float o = (e & 1) ? fmaf(part, cs.y, val * cs.x)
                            : fmaf(-part, cs.y, val * cs.x);
          qk_dst[(size_t)mg * 512 + e] = f2bf(o);
        }
      }
    } else {
#pragma unroll
      for (int m = 0; m < 2; ++m) {
        int rowb0 = m0 + wr * 64 + m * 32 + 4 * hi;
#pragma unroll
        for (int q = 0; q < 4; ++q) {
          int rowb = rowb0 + 8 * q;
          int bidx = rowb >> 10;
          int cpos = rowb & (CTXN - 1);
          ushort4 pk;
          pk.x = f2bf(acc[m][n][q * 4 + 0] + bsv);
          pk.y = f2bf(acc[m][n][q * 4 + 1] + bsv);
          pk.z = f2bf(acc[m][n][q * 4 + 2] + bsv);
          pk.w = f2bf(acc[m][n][q * 4 + 3] + bsv);
          *(ushort4*)(vt + ((size_t)bidx * 512 + e) * 1024 + cpos) = pk;  // vt[b][d][c]
        }
      }
    }
  }
}

// ---------------- K3: scores = qrot @ krot^T * scale -> bf16 S (exact triangular grid) ----
__device__ const unsigned char TRI_IT[36] = {0,1,1,2,2,2,3,3,3,3,4,4,4,4,4,5,5,5,5,5,5,
                                             6,6,6,6,6,6,6,7,7,7,7,7,7,7,7};
__device__ const unsigned char TRI_JT[36] = {0,0,1,0,1,2,0,1,2,3,0,1,2,3,4,0,1,2,3,4,5,
                                             0,1,2,3,4,5,6,0,1,2,3,4,5,6,7};

__global__ __launch_bounds__(256) void scores_kernel(const unsigned short* __restrict__ qr,
                                                     const unsigned short* __restrict__ kr,
                                                     unsigned short* __restrict__ S) {
  int it = TRI_IT[blockIdx.x], jt = TRI_JT[blockIdx.x], b = blockIdx.y;
  __shared__ __align__(16) unsigned short sA[2 * 8192];
  __shared__ __align__(16) unsigned short sB[2 * 8192];
  int t = threadIdx.x, w = t >> 6, l = t & 63, wr = w >> 1, wc = w & 1;
  int cl = l & 31, hi = l >> 5;
  const unsigned short* A  = qr + ((size_t)b << 19) + (size_t)it * 128 * 512;
  const unsigned short* Bp = kr + ((size_t)b << 19) + (size_t)jt * 128 * 512;
  f32x16 acc[2][2] = {};
  gemm_pipe(A, 512, Bp, 512, 8, sA, sB, t, acc);

  const float scale = 0.04419417382415922f;  // 1/sqrt(512)
  unsigned short* Sb = S + ((size_t)b << 20);
#pragma unroll
  for (int m = 0; m < 2; ++m) {
    int iqb = it * 128 + wr * 64 + m * 32 + 4 * hi;
#pragma unroll
    for (int n = 0; n < 2; ++n) {
      int j = jt * 128 + wc * 64 + n * 32 + cl;
#pragma unroll
      for (int r = 0; r < 16; ++r)
        Sb[(size_t)(iqb + (r & 3) + 8 * (r >> 2)) * 1024 + j] = f2bf(acc[m][n][r] * scale);
    }
  }
}

// ---------------- K4: causal row softmax (bf16 in/out), vectorized, one wave/row ----------
__global__ __launch_bounds__(256) void softmax_kernel(const unsigned short* __restrict__ S,
                                                      unsigned short* __restrict__ P) {
  int w = threadIdx.x >> 6, l = threadIdx.x & 63;
  int i = blockIdx.x * 4 + w;              // row 0..1023
  int b = blockIdx.y;
  const unsigned short* row = S + ((size_t)b << 20) + (size_t)i * 1024;
  unsigned short* prow = P + ((size_t)b << 20) + (size_t)i * 1024;
  int len  = i + 1;
  int jmax = ((i >> 7) + 1) << 7;          // zero-fill to end of diagonal 128-tile
  float v[16];
  float mx = -3.4e38f;
#pragma unroll
  for (int c = 0; c < 2; ++c) {
    short8 raw = *(const short8*)(row + c * 512 + l * 8);
#pragma unroll
    for (int jj = 0; jj < 8; ++jj) {
      int j = c * 512 + l * 8 + jj;
      float f = bf2f((unsigned short)raw[jj]);
      v[c * 8 + jj] = (j < len) ? f : -3.4e38f;
      mx = fmaxf(mx, v[c * 8 + jj]);
    }
  }
#pragma unroll
  for (int o = 32; o > 0; o >>= 1) mx = fmaxf(mx, __shfl_xor(mx, o));
  float sm = 0.0f;
#pragma unroll
  for (int p = 0; p < 16; ++p) {
    int j = (p >> 3) * 512 + l * 8 + (p & 7);
    v[p] = (j < len) ? __expf(v[p] - mx) : 0.0f;
    sm += v[p];
  }
#pragma unroll
  for (int o = 32; o > 0; o >>= 1) sm += __shfl_xor(sm, o);
  float inv = 1.0f / sm;
#pragma unroll
  for (int c = 0; c < 2; ++c) {
    int jbase = c * 512 + l * 8;
    if (jbase < jmax) {
      short8 outv;
#pragma unroll
      for (int jj = 0; jj < 8; ++jj) outv[jj] = (short)f2bf(v[c * 8 + jj] * inv);
      *(short8*)(prow + jbase) = outv;
    }
  }
}

// ---------------- K5: out = P @ V  (A=P [1024,1024] bf16, B=vt = V^T [512,1024]) ----------
__global__ __launch_bounds__(256) void pv_kernel(const unsigned short* __restrict__ P,
                                                 const unsigned short* __restrict__ vt,
                                                 float* __restrict__ out) {
  int it = blockIdx.x, nt2 = blockIdx.y, b = blockIdx.z;
  __shared__ __align__(16) unsigned short sA[2 * 8192];
  __shared__ __align__(16) unsigned short sB[2 * 8192];
  int t = threadIdx.x, w = t >> 6, l = t & 63, wr = w >> 1, wc = w & 1;
  int cl = l & 31, hi = l >> 5;
  const unsigned short* A  = P  + ((size_t)b << 20) + (size_t)it * 128 * 1024;
  const unsigned short* Bp = vt + ((size_t)b << 19) + (size_t)nt2 * 128 * 1024;
  int nt = (it + 1) * 2;   // causal: K-tiles of 64 up to (it+1)*128
  f32x16 acc[2][2] = {};
  gemm_pipe(A, 1024, Bp, 1024, nt, sA, sB, t, acc);

  float* ob = out + ((size_t)b << 19);
#pragma unroll
  for (int m = 0; m < 2; ++m) {
    int iqb = it * 128 + wr * 64 + m * 32 + 4 * hi;
#pragma unroll
    for (int n = 0; n < 2; ++n) {
      int d = nt2 * 128 + wc * 64 + n * 32 + cl;
#pragma unroll
      for (int r = 0; r < 16; ++r)
        ob[(size_t)(iqb + (r & 3) + 8 * (r >> 2)) * 512 + d] = acc[m][n][r];
    }
  }
}

// ---------------- launch ----------------
extern "C" void kernel_launch(void* const* d_in, const int* in_sizes, int n_in,
                              void* d_out, int out_size, void* d_ws, size_t ws_size,
                              hipStream_t stream) {
  const float* x  = (const float*)d_in[0];
  const float* wq = (const float*)d_in[1];
  const float* bq = (const float*)d_in[2];
  const float* wk = (const float*)d_in[3];
  const float* bk = (const float*)d_in[4];
  const float* wv = (const float*)d_in[5];
  const float* bv = (const float*)d_in[6];
  float* out = (float*)d_out;

  char* ws = (char*)d_ws;
  float2*         tab  = (float2*)(ws);                          //  2 MB
  unsigned short* xb   = (unsigned short*)(ws + (2ull  << 20));  //  8 MB
  unsigned short* wb   = (unsigned short*)(ws + (10ull << 20));  //  1.5 MB
  unsigned short* qrot = (unsigned short*)(ws + (12ull << 20));  //  8 MB
  unsigned short* krot = (unsigned short*)(ws + (20ull << 20));  //  8 MB
  unsigned short* vt   = (unsigned short*)(ws + (28ull << 20));  //  8 MB
  unsigned short* S    = (unsigned short*)(ws + (36ull << 20));  // 16 MB
  unsigned short* P    = (unsigned short*)(ws + (52ull << 20));  // 16 MB -> total 68 MB

  prep_all<<<dim3(CAST_BLOCKS + CTXN), dim3(256), 0, stream>>>(x, wq, wk, wv, xb, wb, tab);
  qkv_kernel<<<dim3(64, 12), dim3(256), 0, stream>>>(xb, wb, bq, bk, bv, tab, qrot, krot, vt);
  scores_kernel<<<dim3(36, BATCH), dim3(256), 0, stream>>>(qrot, krot, S);
  softmax_kernel<<<dim3(256, BATCH), dim3(256), 0, stream>>>(S, P);
  pv_kernel<<<dim3(8, 4, BATCH), dim3(256), 0, stream>>>(P, vt, out);
}